// Round 10
// baseline (128.397 us; speedup 1.0000x reference)
//
#include <hip/hip_runtime.h>
#include <math.h>

#define NQ     9
#define B_DIM  48
#define S_DIM  96
#define D_DIM  54
#define DENC   4
#define DVAR   8
#define NFLAT  (B_DIM * S_DIM)   // 4608

typedef float f32x2 __attribute__((ext_vector_type(2)));

// Lane-xor primitives — R5/R8 hardware-validated set.
template<int LM>
__device__ __forceinline__ float lx(float v, int lane) {
    int x = __float_as_int(v);
    if constexpr (LM == 1)       x = __builtin_amdgcn_update_dpp(x, x, 0xB1, 0xF, 0xF, true);  // quad[1,0,3,2]
    else if constexpr (LM == 2)  x = __builtin_amdgcn_update_dpp(x, x, 0x4E, 0xF, 0xF, true);  // quad[2,3,0,1]
    else if constexpr (LM == 4)  x = __builtin_amdgcn_ds_swizzle(x, 0x101F);                   // xor4
    else if constexpr (LM == 8)  x = __builtin_amdgcn_update_dpp(x, x, 0x128, 0xF, 0xF, true); // ROW_ROR:8
    else if constexpr (LM == 16) x = __builtin_amdgcn_ds_swizzle(x, 0x401F);                   // xor16
    else {
        auto r = __builtin_amdgcn_permlane32_swap(x, x, false, false);
        // ret[0] = [lo,lo], ret[1] = [hi,hi]; want [hi,lo]
        x = (lane & 32) ? r[0] : r[1];
    }
    return __int_as_float(x);
}

__device__ __forceinline__ float wave_sum(float v, int lane) {
    v += lx<32>(v, lane);
    v += lx<16>(v, lane);
    v += lx<8>(v, lane);
    v += lx<4>(v, lane);
    v += lx<2>(v, lane);
    v += lx<1>(v, lane);
    return v;
}

// State layout: amp index i (9 bits) -> lane = i>>3 (bits 8..3), reg r = i&7 (bits 2..0).
// Qubit j <-> state bit BJ = 8-j.

__device__ __forceinline__ float bperm(int addr, float v) {
    return __int_as_float(__builtin_amdgcn_ds_bpermute(addr, __float_as_int(v)));
}

// CNOT ring (control j, target (j+1)%9): stages (8,7)..(4,3) collapse to the
// Gray-code lane permutation dst L <- src L^(L>>1), one ds_bpermute per word
// (R8-validated). Then reg-local fixups + xor32 stage.
__device__ __forceinline__ void ring(f32x2 st[8], int lane) {
    const int gray = (lane ^ (lane >> 1)) << 2;
#pragma unroll
    for (int r = 0; r < 8; ++r) {
        st[r].x = bperm(gray, st[r].x);
        st[r].y = bperm(gray, st[r].y);
    }
    // (3,2): ctrl lane bit0 (b3), tgt reg bit2
    {
        const bool c0 = (lane & 1) != 0;
#pragma unroll
        for (int r = 0; r < 4; ++r) {
            f32x2 a = st[r], b = st[r + 4];
            st[r]     = c0 ? b : a;
            st[r + 4] = c0 ? a : b;
        }
    }
    // (2,1): regs with bit2: r <-> r^2 (rename)
    { f32x2 t = st[4]; st[4] = st[6]; st[6] = t; }
    { f32x2 t = st[5]; st[5] = st[7]; st[7] = t; }
    // (1,0): regs with bit1: r <-> r^1 (rename)
    { f32x2 t = st[2]; st[2] = st[3]; st[3] = t; }
    { f32x2 t = st[6]; st[6] = st[7]; st[7] = t; }
    // (0,8): odd regs: xor32
#pragma unroll
    for (int r = 1; r < 8; r += 2) {
        st[r].x = lx<32>(st[r].x, lane);
        st[r].y = lx<32>(st[r].y, lane);
    }
}

template<int BJ>
__device__ __forceinline__ void rot_ry(f32x2 st[8], float c, float s, int lane) {
    const f32x2 c2 = {c, c};
    if constexpr (BJ >= 3) {
        constexpr int lm = 1 << (BJ - 3);
        const float sg = (lane & lm) ? s : -s;
        const f32x2 sg2 = {sg, sg};
#pragma unroll
        for (int r = 0; r < 8; ++r) {
            f32x2 p = { lx<lm>(st[r].x, lane), lx<lm>(st[r].y, lane) };
            st[r] = st[r] * c2 + p * sg2;
        }
    } else {
        constexpr int M = 1 << BJ;
        const f32x2 s2 = {s, s}, ns2 = {-s, -s};
#pragma unroll
        for (int r = 0; r < 8; ++r) {
            if ((r & M) == 0) {
                f32x2 a = st[r], b = st[r + M];
                st[r]     = a * c2 + b * ns2;
                st[r + M] = b * c2 + a * s2;
            }
        }
    }
}

template<int BJ>
__device__ __forceinline__ void rot_rx(f32x2 st[8], float c, float s, int lane) {
    if constexpr (BJ >= 3) {
        constexpr int lm = 1 << (BJ - 3);
#pragma unroll
        for (int r = 0; r < 8; ++r) {
            float px = lx<lm>(st[r].x, lane), py = lx<lm>(st[r].y, lane);
            float nx = fmaf(s, py, c * st[r].x);
            float ny = fmaf(-s, px, c * st[r].y);
            st[r].x = nx; st[r].y = ny;
        }
    } else {
        constexpr int M = 1 << BJ;
#pragma unroll
        for (int r = 0; r < 8; ++r) {
            if ((r & M) == 0) {
                f32x2 a = st[r], b = st[r + M];
                st[r].x     = fmaf(s, b.y, c * a.x);
                st[r].y     = fmaf(-s, b.x, c * a.y);
                st[r + M].x = fmaf(s, a.y, c * b.x);
                st[r + M].y = fmaf(-s, a.x, c * b.y);
            }
        }
    }
}

#define INITQ(j) { f32x2 c0 = cs[2 * (j)], c1 = cs[2 * (j) + 1];      \
                   rot_rx<8 - (j)>(st, c0.x, c0.y, lane);             \
                   rot_ry<8 - (j)>(st, c1.x, c1.y, lane); }

__device__ __forceinline__ void run_circuit(f32x2 st[8], const f32x2* cs, int layers, int lane) {
    INITQ(0) INITQ(1) INITQ(2) INITQ(3) INITQ(4)
    INITQ(5) INITQ(6) INITQ(7) INITQ(8)
    const f32x2* p = cs + 18;
#pragma unroll 1
    for (int L = 0; L < layers; ++L) {
        ring(st, lane);
        { f32x2 cc = p[0]; rot_ry<8>(st, cc.x, cc.y, lane); }
        { f32x2 cc = p[1]; rot_ry<7>(st, cc.x, cc.y, lane); }
        { f32x2 cc = p[2]; rot_ry<6>(st, cc.x, cc.y, lane); }
        { f32x2 cc = p[3]; rot_ry<5>(st, cc.x, cc.y, lane); }
        { f32x2 cc = p[4]; rot_ry<4>(st, cc.x, cc.y, lane); }
        { f32x2 cc = p[5]; rot_ry<3>(st, cc.x, cc.y, lane); }
        { f32x2 cc = p[6]; rot_ry<2>(st, cc.x, cc.y, lane); }
        { f32x2 cc = p[7]; rot_ry<1>(st, cc.x, cc.y, lane); }
        { f32x2 cc = p[8]; rot_ry<0>(st, cc.x, cc.y, lane); }
        p += 9;
    }
}

// <Z>, <X>, <Y> on qubit with state-bit BJ.
template<int BJ>
__device__ __forceinline__ void expv(const f32x2 st[8], int lane, float& ez, float& ex, float& ey) {
    ez = ex = ey = 0.f;
    if constexpr (BJ >= 3) {
        constexpr int lm = 1 << (BJ - 3);
        const float sgn = (lane & lm) ? -1.f : 1.f;
#pragma unroll
        for (int r = 0; r < 8; ++r) {
            float px = lx<lm>(st[r].x, lane);
            float py = lx<lm>(st[r].y, lane);
            ez += sgn * (st[r].x * st[r].x + st[r].y * st[r].y);
            ex += st[r].x * px + st[r].y * py;
            ey += sgn * (st[r].x * py - st[r].y * px);
        }
    } else {
        constexpr int M = 1 << BJ;
#pragma unroll
        for (int r = 0; r < 8; ++r) {
            if ((r & M) == 0) {
                f32x2 a = st[r], b = st[r + M];
                ez += (a.x * a.x + a.y * a.y) - (b.x * b.x + b.y * b.y);
                ex += 2.f * (a.x * b.x + a.y * b.y);
                ey += 2.f * (a.x * b.y - a.y * b.x);
            }
        }
    }
    ez = wave_sum(ez, lane); ex = wave_sum(ex, lane); ey = wave_sum(ey, lane);
}

__global__ __launch_bounds__(64) void sim_kernel(
    const float* __restrict__ inp, const float* __restrict__ wq,
    const float* __restrict__ wk,  const float* __restrict__ wv,
    float* __restrict__ outQ, float* __restrict__ outK, float* __restrict__ outV)
{
    __shared__ f32x2 cs[54 + 270];   // {cos(t/2), sin(t/2)} per angle

    const int lane = threadIdx.x;
    const int fi   = blockIdx.x;     // flat = s*B + b; 4608 waves = 18/CU
    const int b = fi % B_DIM, s = fi / B_DIM;
    const float* x = inp + ((size_t)b * S_DIM + s) * D_DIM;

    for (int k = lane; k < 324; k += 64) {
        float ang = (k < 54)  ? x[k]
                  : (k < 144) ? wq[k - 54]
                  : (k < 234) ? wk[k - 144]
                              : wv[k - 234];
        float sn, cn; sincosf(0.5f * ang, &sn, &cn);
        f32x2 v = {cn, sn};
        cs[k] = v;
    }
    // single wave: LDS write->read ordering handled by lgkmcnt, no barrier needed

    f32x2 st[8], ck[8];
#pragma unroll
    for (int r = 0; r < 8; ++r) { f32x2 z = {0.f, 0.f}; st[r] = z; }
    if (lane == 0) st[0].x = 1.f;

    // Shared encoding circuit, checkpoint in registers (2 live states max).
    run_circuit(st, cs, DENC, lane);
#pragma unroll
    for (int r = 0; r < 8; ++r) ck[r] = st[r];

    // ---- Q ----
    run_circuit(st, cs + 54, DVAR, lane);
    {
        float p = 0.f;
#pragma unroll
        for (int r = 0; r < 8; ++r) p += st[r].x * st[r].x + st[r].y * st[r].y;
        p = (lane & 32) ? -p : p;     // qubit 0 = state bit 8 = lane bit 5
        p = wave_sum(p, lane);
        if (lane == 0) outQ[fi] = p;
    }

    // ---- K ----
#pragma unroll
    for (int r = 0; r < 8; ++r) st[r] = ck[r];
    run_circuit(st, cs + 144, DVAR, lane);
    {
        float p = 0.f;
#pragma unroll
        for (int r = 0; r < 8; ++r) p += st[r].x * st[r].x + st[r].y * st[r].y;
        p = (lane & 32) ? -p : p;
        p = wave_sum(p, lane);
        if (lane == 0) outK[fi] = p;
    }

    // ---- V ----
#pragma unroll
    for (int r = 0; r < 8; ++r) st[r] = ck[r];
    run_circuit(st, cs + 234, DVAR, lane);
    {
        float* vrow = outV + (size_t)fi * D_DIM;
#define EXPQ(q) { float ez, ex, ey; expv<8 - (q)>(st, lane, ez, ex, ey);            \
                  if (lane == 0) { vrow[(q)] = ez; vrow[9 + (q)] = ex;              \
                                   vrow[18 + (q)] = ey; vrow[27 + (q)] = ez;        \
                                   vrow[36 + (q)] = ex; vrow[45 + (q)] = ey; } }
        EXPQ(0) EXPQ(1) EXPQ(2) EXPQ(3) EXPQ(4)
        EXPQ(5) EXPQ(6) EXPQ(7) EXPQ(8)
#undef EXPQ
    }
}

__global__ __launch_bounds__(256) void attn_kernel(
    const float* __restrict__ inp, const float* __restrict__ Q,
    const float* __restrict__ K,   const float* __restrict__ V,
    float* __restrict__ out)
{
    __shared__ float w4[4][S_DIM];
    const int warp = threadIdx.x >> 6;
    const int t    = threadIdx.x & 63;
    const int bi   = blockIdx.x * 4 + warp;   // b*S + i
    const int b    = bi / S_DIM;
    const int i    = bi % S_DIM;
    float* w = w4[warp];

    const float q = Q[i * B_DIM + b];
    float e0, e1 = 0.f;
    {
        float d0 = q - K[t * B_DIM + b];
        e0 = expf(-d0 * d0);
        w[t] = e0;
        if (t < S_DIM - 64) {
            float d1 = q - K[(t + 64) * B_DIM + b];
            e1 = expf(-d1 * d1);
            w[t + 64] = e1;
        }
    }
    float ps = wave_sum(e0 + e1, t);
    const float inv = 1.f / ps;

    if (t < D_DIM) {
        float acc = 0.f;
        for (int j = 0; j < S_DIM; ++j)
            acc += w[j] * V[(size_t)(j * B_DIM + b) * D_DIM + t];
        size_t o = (size_t)bi * D_DIM + t;
        out[o] = inp[o] + acc * inv;
    }
}

extern "C" void kernel_launch(void* const* d_in, const int* in_sizes, int n_in,
                              void* d_out, int out_size, void* d_ws, size_t ws_size,
                              hipStream_t stream)
{
    (void)in_sizes; (void)n_in; (void)out_size; (void)ws_size;
    const float* inp = (const float*)d_in[0];
    const float* wq  = (const float*)d_in[1];
    const float* wk  = (const float*)d_in[2];
    const float* wv  = (const float*)d_in[3];
    float* outp = (float*)d_out;

    float* Qw = (float*)d_ws;
    float* Kw = Qw + NFLAT;
    float* Vw = Kw + NFLAT;

    sim_kernel<<<NFLAT, 64, 0, stream>>>(inp, wq, wk, wv, Qw, Kw, Vw);
    attn_kernel<<<NFLAT / 4, 256, 0, stream>>>(inp, Qw, Kw, Vw, outp);
}

// Round 11
// 109.493 us; speedup vs baseline: 1.1727x; 1.1727x over previous
//
#include <hip/hip_runtime.h>
#include <math.h>

#define B_DIM  48
#define S_DIM  96
#define D_DIM  54
#define DENC   4
#define DVAR   8
#define NFLAT  (B_DIM * S_DIM)   // 4608

// One complex amplitude = one 32-bit reg: (x=re in lo16, y=im in hi16), f16.
typedef _Float16 h2 __attribute__((ext_vector_type(2)));

__device__ __forceinline__ int h2i(h2 v) { return __builtin_bit_cast(int, v); }
__device__ __forceinline__ h2  i2h(int v) { return __builtin_bit_cast(h2, v); }

// Lane-xor primitives on 32-bit patterns — R5/R8/R10 hardware-validated set.
template<int LM>
__device__ __forceinline__ int lxi(int x, int lane) {
    if constexpr (LM == 1)       return __builtin_amdgcn_update_dpp(x, x, 0xB1, 0xF, 0xF, true);  // quad[1,0,3,2]
    else if constexpr (LM == 2)  return __builtin_amdgcn_update_dpp(x, x, 0x4E, 0xF, 0xF, true);  // quad[2,3,0,1]
    else if constexpr (LM == 4)  return __builtin_amdgcn_ds_swizzle(x, 0x101F);                   // xor4
    else if constexpr (LM == 8)  return __builtin_amdgcn_update_dpp(x, x, 0x128, 0xF, 0xF, true); // ROW_ROR:8
    else if constexpr (LM == 16) return __builtin_amdgcn_ds_swizzle(x, 0x401F);                   // xor16
    else {
        auto r = __builtin_amdgcn_permlane32_swap(x, x, false, false);
        // ret[0] = [lo,lo], ret[1] = [hi,hi]; want [hi,lo]
        return (lane & 32) ? r[0] : r[1];
    }
}
template<int LM>
__device__ __forceinline__ float lx(float v, int lane) {
    return __int_as_float(lxi<LM>(__float_as_int(v), lane));
}

__device__ __forceinline__ float wave_sum(float v, int lane) {
    v += lx<32>(v, lane);
    v += lx<16>(v, lane);
    v += lx<8>(v, lane);
    v += lx<4>(v, lane);
    v += lx<2>(v, lane);
    v += lx<1>(v, lane);
    return v;
}

// State layout: amp index i (9 bits) -> lane = i>>3 (bits 8..3), reg r = i&7 (bits 2..0).
// Qubit j <-> state bit BJ = 8-j.

// halves-swap (y,x) <- (x,y): one v_alignbit
__device__ __forceinline__ h2 hswap(h2 v) {
    int p = h2i(v);
    return i2h(__builtin_amdgcn_alignbit(p, p, 16));
}

// CNOT ring (control j, target (j+1)%9): stages (8,7)..(4,3) = Gray-code lane
// permutation dst L <- src L^(L>>1), ONE ds_bpermute per amplitude (R8-validated),
// then reg-local fixups + xor32 stage.
__device__ __forceinline__ void ring(h2 st[8], int lane) {
    const int gray = (lane ^ (lane >> 1)) << 2;
#pragma unroll
    for (int r = 0; r < 8; ++r)
        st[r] = i2h(__builtin_amdgcn_ds_bpermute(gray, h2i(st[r])));
    // (3,2): ctrl lane bit0 (b3), tgt reg bit2
    {
        const bool c0 = (lane & 1) != 0;
#pragma unroll
        for (int r = 0; r < 4; ++r) {
            h2 a = st[r], b = st[r + 4];
            st[r]     = c0 ? b : a;
            st[r + 4] = c0 ? a : b;
        }
    }
    // (2,1): regs with bit2: r <-> r^2 (rename)
    { h2 t = st[4]; st[4] = st[6]; st[6] = t; }
    { h2 t = st[5]; st[5] = st[7]; st[7] = t; }
    // (1,0): regs with bit1: r <-> r^1 (rename)
    { h2 t = st[2]; st[2] = st[3]; st[3] = t; }
    { h2 t = st[6]; st[6] = st[7]; st[7] = t; }
    // (0,8): odd regs: xor32
#pragma unroll
    for (int r = 1; r < 8; r += 2)
        st[r] = i2h(lxi<32>(h2i(st[r]), lane));
}

// RY(theta): n0 = c*a0 - s*a1 ; n1 = s*a0 + c*a1.  c2i=(c,c), s2i=(s,s) as packed f16.
template<int BJ>
__device__ __forceinline__ void rot_ry(h2 st[8], int c2i, int s2i, int lane) {
    const h2 c2 = i2h(c2i);
    if constexpr (BJ >= 3) {
        constexpr int lm = 1 << (BJ - 3);
        const h2 sg = i2h((lane & lm) ? s2i : (s2i ^ 0x80008000)); // side1:+s, side0:-s
#pragma unroll
        for (int r = 0; r < 8; ++r) {
            h2 p = i2h(lxi<lm>(h2i(st[r]), lane));
            st[r] = st[r] * c2 + p * sg;     // v_pk_mul_f16 + v_pk_fma_f16
        }
    } else {
        constexpr int M = 1 << BJ;
        const h2 s2 = i2h(s2i), ns2 = i2h(s2i ^ 0x80008000);
#pragma unroll
        for (int r = 0; r < 8; ++r) {
            if ((r & M) == 0) {
                h2 a = st[r], b = st[r + M];
                st[r]     = a * c2 + b * ns2;
                st[r + M] = b * c2 + a * s2;
            }
        }
    }
}

// RX(theta): n0 = c*a0 - i*s*a1 -> (c*x0 + s*y1, c*y0 - s*x1); symmetric for n1.
// st_new = c2*st + (s,-s) * hswap(partner).
template<int BJ>
__device__ __forceinline__ void rot_rx(h2 st[8], int c2i, int s2i, int lane) {
    const h2 c2 = i2h(c2i);
    const h2 sm = i2h(s2i ^ 0x80000000);   // (s, -s)
    if constexpr (BJ >= 3) {
        constexpr int lm = 1 << (BJ - 3);
#pragma unroll
        for (int r = 0; r < 8; ++r) {
            h2 p = i2h(lxi<lm>(h2i(st[r]), lane));
            st[r] = st[r] * c2 + hswap(p) * sm;
        }
    } else {
        constexpr int M = 1 << BJ;
#pragma unroll
        for (int r = 0; r < 8; ++r) {
            if ((r & M) == 0) {
                h2 a = st[r], b = st[r + M];
                st[r]     = a * c2 + hswap(b) * sm;
                st[r + M] = b * c2 + hswap(a) * sm;
            }
        }
    }
}

#define INITQ(j) { rot_rx<8 - (j)>(st, cc[2 * (j)],     ss[2 * (j)],     lane);  \
                   rot_ry<8 - (j)>(st, cc[2 * (j) + 1], ss[2 * (j) + 1], lane); }

// cc/ss: per-angle packed (c,c) and (s,s) tables for this circuit segment.
__device__ __forceinline__ void run_circuit(h2 st[8], const int* cc, const int* ss,
                                            int layers, int lane) {
    INITQ(0) INITQ(1) INITQ(2) INITQ(3) INITQ(4)
    INITQ(5) INITQ(6) INITQ(7) INITQ(8)
    const int* pc = cc + 18;
    const int* ps = ss + 18;
#pragma unroll 1
    for (int L = 0; L < layers; ++L) {
        ring(st, lane);
        rot_ry<8>(st, pc[0], ps[0], lane);
        rot_ry<7>(st, pc[1], ps[1], lane);
        rot_ry<6>(st, pc[2], ps[2], lane);
        rot_ry<5>(st, pc[3], ps[3], lane);
        rot_ry<4>(st, pc[4], ps[4], lane);
        rot_ry<3>(st, pc[5], ps[5], lane);
        rot_ry<2>(st, pc[6], ps[6], lane);
        rot_ry<1>(st, pc[7], ps[7], lane);
        rot_ry<0>(st, pc[8], ps[8], lane);
        pc += 9; ps += 9;
    }
}

// <Z>, <X>, <Y> on qubit with state-bit BJ (f32 accumulation).
template<int BJ>
__device__ __forceinline__ void expv(const h2 st[8], int lane, float& ez, float& ex, float& ey) {
    ez = ex = ey = 0.f;
    if constexpr (BJ >= 3) {
        constexpr int lm = 1 << (BJ - 3);
        const float sgn = (lane & lm) ? -1.f : 1.f;
#pragma unroll
        for (int r = 0; r < 8; ++r) {
            h2 p = i2h(lxi<lm>(h2i(st[r]), lane));
            float x = (float)st[r].x, y = (float)st[r].y;
            float px = (float)p.x,   py = (float)p.y;
            ez += sgn * (x * x + y * y);
            ex += x * px + y * py;            // both halves -> 2*Re total
            ey += sgn * (x * py - y * px);    // both halves -> 2*Im total
        }
    } else {
        constexpr int M = 1 << BJ;
#pragma unroll
        for (int r = 0; r < 8; ++r) {
            if ((r & M) == 0) {
                float ax = (float)st[r].x,     ay = (float)st[r].y;
                float bx = (float)st[r + M].x, by = (float)st[r + M].y;
                ez += (ax * ax + ay * ay) - (bx * bx + by * by);
                ex += 2.f * (ax * bx + ay * by);
                ey += 2.f * (ax * by - ay * bx);
            }
        }
    }
    ez = wave_sum(ez, lane); ex = wave_sum(ex, lane); ey = wave_sum(ey, lane);
}

__global__ __launch_bounds__(64) void sim_kernel(
    const float* __restrict__ inp, const float* __restrict__ wq,
    const float* __restrict__ wk,  const float* __restrict__ wv,
    float* __restrict__ outQ, float* __restrict__ outK, float* __restrict__ outV)
{
    __shared__ int csc[324];   // packed (c,c) f16 pairs
    __shared__ int css[324];   // packed (s,s) f16 pairs

    const int lane = threadIdx.x;
    const int fi   = blockIdx.x;     // flat = s*B + b; 4608 waves = 18/CU
    const int b = fi % B_DIM, s = fi / B_DIM;
    const float* x = inp + ((size_t)b * S_DIM + s) * D_DIM;

    for (int k = lane; k < 324; k += 64) {
        float ang = (k < 54)  ? x[k]
                  : (k < 144) ? wq[k - 54]
                  : (k < 234) ? wk[k - 144]
                              : wv[k - 234];
        float sn, cn; sincosf(0.5f * ang, &sn, &cn);
        _Float16 hc = (_Float16)cn, hs = (_Float16)sn;
        h2 c2 = {hc, hc}, s2 = {hs, hs};
        csc[k] = h2i(c2);
        css[k] = h2i(s2);
    }
    // single wave: LDS write->read ordering handled by lgkmcnt, no barrier needed

    h2 st[8], ck[8];
#pragma unroll
    for (int r = 0; r < 8; ++r) st[r] = i2h(0);
    if (lane == 0) { h2 one = {(_Float16)1.f, (_Float16)0.f}; st[0] = one; }

    // Shared encoding circuit, checkpoint in registers.
    run_circuit(st, csc, css, DENC, lane);
#pragma unroll
    for (int r = 0; r < 8; ++r) ck[r] = st[r];

    // ---- Q ----
    run_circuit(st, csc + 54, css + 54, DVAR, lane);
    {
        float p = 0.f;
#pragma unroll
        for (int r = 0; r < 8; ++r) {
            float xx = (float)st[r].x, yy = (float)st[r].y;
            p += xx * xx + yy * yy;
        }
        p = (lane & 32) ? -p : p;     // qubit 0 = state bit 8 = lane bit 5
        p = wave_sum(p, lane);
        if (lane == 0) outQ[fi] = p;
    }

    // ---- K ----
#pragma unroll
    for (int r = 0; r < 8; ++r) st[r] = ck[r];
    run_circuit(st, csc + 144, css + 144, DVAR, lane);
    {
        float p = 0.f;
#pragma unroll
        for (int r = 0; r < 8; ++r) {
            float xx = (float)st[r].x, yy = (float)st[r].y;
            p += xx * xx + yy * yy;
        }
        p = (lane & 32) ? -p : p;
        p = wave_sum(p, lane);
        if (lane == 0) outK[fi] = p;
    }

    // ---- V ----
#pragma unroll
    for (int r = 0; r < 8; ++r) st[r] = ck[r];
    run_circuit(st, csc + 234, css + 234, DVAR, lane);
    {
        float* vrow = outV + (size_t)fi * D_DIM;
#define EXPQ(q) { float ez, ex, ey; expv<8 - (q)>(st, lane, ez, ex, ey);            \
                  if (lane == 0) { vrow[(q)] = ez; vrow[9 + (q)] = ex;              \
                                   vrow[18 + (q)] = ey; vrow[27 + (q)] = ez;        \
                                   vrow[36 + (q)] = ex; vrow[45 + (q)] = ey; } }
        EXPQ(0) EXPQ(1) EXPQ(2) EXPQ(3) EXPQ(4)
        EXPQ(5) EXPQ(6) EXPQ(7) EXPQ(8)
#undef EXPQ
    }
}

__global__ __launch_bounds__(256) void attn_kernel(
    const float* __restrict__ inp, const float* __restrict__ Q,
    const float* __restrict__ K,   const float* __restrict__ V,
    float* __restrict__ out)
{
    __shared__ float w4[4][S_DIM];
    const int warp = threadIdx.x >> 6;
    const int t    = threadIdx.x & 63;
    const int bi   = blockIdx.x * 4 + warp;   // b*S + i
    const int b    = bi / S_DIM;
    const int i    = bi % S_DIM;
    float* w = w4[warp];

    const float q = Q[i * B_DIM + b];
    float e0, e1 = 0.f;
    {
        float d0 = q - K[t * B_DIM + b];
        e0 = expf(-d0 * d0);
        w[t] = e0;
        if (t < S_DIM - 64) {
            float d1 = q - K[(t + 64) * B_DIM + b];
            e1 = expf(-d1 * d1);
            w[t + 64] = e1;
        }
    }
    float ps = wave_sum(e0 + e1, t);
    const float inv = 1.f / ps;

    if (t < D_DIM) {
        float acc = 0.f;
        for (int j = 0; j < S_DIM; ++j)
            acc += w[j] * V[(size_t)(j * B_DIM + b) * D_DIM + t];
        size_t o = (size_t)bi * D_DIM + t;
        out[o] = inp[o] + acc * inv;
    }
}

extern "C" void kernel_launch(void* const* d_in, const int* in_sizes, int n_in,
                              void* d_out, int out_size, void* d_ws, size_t ws_size,
                              hipStream_t stream)
{
    (void)in_sizes; (void)n_in; (void)out_size; (void)ws_size;
    const float* inp = (const float*)d_in[0];
    const float* wq  = (const float*)d_in[1];
    const float* wk  = (const float*)d_in[2];
    const float* wv  = (const float*)d_in[3];
    float* outp = (float*)d_out;

    float* Qw = (float*)d_ws;
    float* Kw = Qw + NFLAT;
    float* Vw = Kw + NFLAT;

    sim_kernel<<<NFLAT, 64, 0, stream>>>(inp, wq, wk, wv, Qw, Kw, Vw);
    attn_kernel<<<NFLAT / 4, 256, 0, stream>>>(inp, Qw, Kw, Vw, outp);
}

// Round 12
// 108.913 us; speedup vs baseline: 1.1789x; 1.0053x over previous
//
#include <hip/hip_runtime.h>
#include <math.h>

#define B_DIM  48
#define S_DIM  96
#define D_DIM  54
#define DENC   4
#define DVAR   8
#define NFLAT  (B_DIM * S_DIM)   // 4608

// One complex amplitude = one 32-bit reg: (x=re in lo16, y=im in hi16), f16.
typedef _Float16 h2 __attribute__((ext_vector_type(2)));

__device__ __forceinline__ int h2i(h2 v) { return __builtin_bit_cast(int, v); }
__device__ __forceinline__ h2  i2h(int v) { return __builtin_bit_cast(h2, v); }

// Lane-xor primitives on 32-bit patterns — R5/R8/R11 hardware-validated set.
template<int LM>
__device__ __forceinline__ int lxi(int x, int lane) {
    if constexpr (LM == 1)       return __builtin_amdgcn_update_dpp(x, x, 0xB1, 0xF, 0xF, true);  // quad[1,0,3,2]
    else if constexpr (LM == 2)  return __builtin_amdgcn_update_dpp(x, x, 0x4E, 0xF, 0xF, true);  // quad[2,3,0,1]
    else if constexpr (LM == 4)  return __builtin_amdgcn_ds_swizzle(x, 0x101F);                   // xor4
    else if constexpr (LM == 8)  return __builtin_amdgcn_update_dpp(x, x, 0x128, 0xF, 0xF, true); // ROW_ROR:8
    else if constexpr (LM == 16) return __builtin_amdgcn_ds_swizzle(x, 0x401F);                   // xor16
    else {
        auto r = __builtin_amdgcn_permlane32_swap(x, x, false, false);
        // ret[0] = [lo,lo], ret[1] = [hi,hi]; want [hi,lo]
        return (lane & 32) ? r[0] : r[1];
    }
}
template<int LM>
__device__ __forceinline__ float lx(float v, int lane) {
    return __int_as_float(lxi<LM>(__float_as_int(v), lane));
}

__device__ __forceinline__ float wave_sum(float v, int lane) {
    v += lx<32>(v, lane);
    v += lx<16>(v, lane);
    v += lx<8>(v, lane);
    v += lx<4>(v, lane);
    v += lx<2>(v, lane);
    v += lx<1>(v, lane);
    return v;
}

// State layout: amp index i (9 bits) -> lane = i>>3 (bits 8..3), reg r = i&7 (bits 2..0).
// Qubit j <-> state bit BJ = 8-j.

// halves-swap (y,x) <- (x,y): one v_alignbit
__device__ __forceinline__ h2 hswap(h2 v) {
    int p = h2i(v);
    return i2h(__builtin_amdgcn_alignbit(p, p, 16));
}

// Reg-local + xor32 tail of the CNOT ring (stages (3,2)(2,1)(1,0)(0,8)) — R11-validated.
__device__ __forceinline__ void ring_tail(h2 st[8], int lane) {
    // (3,2): ctrl lane bit0 (b3), tgt reg bit2
    {
        const bool c0 = (lane & 1) != 0;
#pragma unroll
        for (int r = 0; r < 4; ++r) {
            h2 a = st[r], b = st[r + 4];
            st[r]     = c0 ? b : a;
            st[r + 4] = c0 ? a : b;
        }
    }
    // (2,1): regs with bit2: r <-> r^2 (rename)
    { h2 t = st[4]; st[4] = st[6]; st[6] = t; }
    { h2 t = st[5]; st[5] = st[7]; st[7] = t; }
    // (1,0): regs with bit1: r <-> r^1 (rename)
    { h2 t = st[2]; st[2] = st[3]; st[3] = t; }
    { h2 t = st[6]; st[6] = st[7]; st[7] = t; }
    // (0,8): odd regs: xor32
#pragma unroll
    for (int r = 1; r < 8; r += 2)
        st[r] = i2h(lxi<32>(h2i(st[r]), lane));
}

// CNOT ring on NP states: stages (8,7)..(4,3) = Gray-code lane permutation
// dst L <- src L^(L>>1), one ds_bpermute per amplitude (R8/R11-validated).
// All NP*8 bpermutes issued back-to-back (one lgkmcnt window).
template<int NP>
__device__ __forceinline__ void ringN(h2 st[][8], int lane) {
    const int gray = (lane ^ (lane >> 1)) << 2;
#pragma unroll
    for (int r = 0; r < 8; ++r)
#pragma unroll
        for (int p = 0; p < NP; ++p)
            st[p][r] = i2h(__builtin_amdgcn_ds_bpermute(gray, h2i(st[p][r])));
#pragma unroll
    for (int p = 0; p < NP; ++p)
        ring_tail(st[p], lane);
}

// RY: n0 = c*a0 - s*a1 ; n1 = s*a0 + c*a1.  c2/s2 packed (c,c)/(s,s) per state.
template<int NP, int BJ>
__device__ __forceinline__ void rot_ryN(h2 st[][8], const int* c2, const int* s2, int lane) {
    if constexpr (BJ >= 3) {
        constexpr int lm = 1 << (BJ - 3);
        int sg[NP];
#pragma unroll
        for (int p = 0; p < NP; ++p) sg[p] = (lane & lm) ? s2[p] : (s2[p] ^ 0x80008000);
#pragma unroll
        for (int r = 0; r < 8; ++r) {
#pragma unroll
            for (int p = 0; p < NP; ++p) {
                h2 pt = i2h(lxi<lm>(h2i(st[p][r]), lane));
                st[p][r] = st[p][r] * i2h(c2[p]) + pt * i2h(sg[p]);
            }
        }
    } else {
        constexpr int M = 1 << BJ;
#pragma unroll
        for (int r = 0; r < 8; ++r) {
            if ((r & M) == 0) {
#pragma unroll
                for (int p = 0; p < NP; ++p) {
                    h2 a = st[p][r], b = st[p][r + M];
                    h2 c2h = i2h(c2[p]), s2h = i2h(s2[p]), ns2h = i2h(s2[p] ^ 0x80008000);
                    st[p][r]     = a * c2h + b * ns2h;
                    st[p][r + M] = b * c2h + a * s2h;
                }
            }
        }
    }
}

// RX: n = c*a + (s,-s)*hswap(partner) — R11-validated form.
template<int NP, int BJ>
__device__ __forceinline__ void rot_rxN(h2 st[][8], const int* c2, const int* s2, int lane) {
    if constexpr (BJ >= 3) {
        constexpr int lm = 1 << (BJ - 3);
#pragma unroll
        for (int r = 0; r < 8; ++r) {
#pragma unroll
            for (int p = 0; p < NP; ++p) {
                h2 pt = i2h(lxi<lm>(h2i(st[p][r]), lane));
                st[p][r] = st[p][r] * i2h(c2[p]) + hswap(pt) * i2h(s2[p] ^ 0x80000000);
            }
        }
    } else {
        constexpr int M = 1 << BJ;
#pragma unroll
        for (int r = 0; r < 8; ++r) {
            if ((r & M) == 0) {
#pragma unroll
                for (int p = 0; p < NP; ++p) {
                    h2 a = st[p][r], b = st[p][r + M];
                    h2 c2h = i2h(c2[p]), sm = i2h(s2[p] ^ 0x80000000);
                    st[p][r]     = a * c2h + hswap(b) * sm;
                    st[p][r + M] = b * c2h + hswap(a) * sm;
                }
            }
        }
    }
}

// <Z>, <X>, <Y> on qubit with state-bit BJ (f32 accumulation) — R11-validated.
template<int BJ>
__device__ __forceinline__ void expv(const h2 st[8], int lane, float& ez, float& ex, float& ey) {
    ez = ex = ey = 0.f;
    if constexpr (BJ >= 3) {
        constexpr int lm = 1 << (BJ - 3);
        const float sgn = (lane & lm) ? -1.f : 1.f;
#pragma unroll
        for (int r = 0; r < 8; ++r) {
            h2 p = i2h(lxi<lm>(h2i(st[r]), lane));
            float x = (float)st[r].x, y = (float)st[r].y;
            float px = (float)p.x,   py = (float)p.y;
            ez += sgn * (x * x + y * y);
            ex += x * px + y * py;            // both halves -> 2*Re total
            ey += sgn * (x * py - y * px);    // both halves -> 2*Im total
        }
    } else {
        constexpr int M = 1 << BJ;
#pragma unroll
        for (int r = 0; r < 8; ++r) {
            if ((r & M) == 0) {
                float ax = (float)st[r].x,     ay = (float)st[r].y;
                float bx = (float)st[r + M].x, by = (float)st[r + M].y;
                ez += (ax * ax + ay * ay) - (bx * bx + by * by);
                ex += 2.f * (ax * bx + ay * by);
                ey += 2.f * (ax * by - ay * bx);
            }
        }
    }
    ez = wave_sum(ez, lane); ex = wave_sum(ex, lane); ey = wave_sum(ey, lane);
}

__global__ __launch_bounds__(64) void sim_kernel(
    const float* __restrict__ inp, const float* __restrict__ wq,
    const float* __restrict__ wk,  const float* __restrict__ wv,
    float* __restrict__ outQ, float* __restrict__ outK, float* __restrict__ outV)
{
    __shared__ int csc[324];   // packed (c,c) f16 pairs
    __shared__ int css[324];   // packed (s,s) f16 pairs

    const int lane = threadIdx.x;
    const int fi   = blockIdx.x;     // flat = s*B + b; 4608 waves = 18/CU
    const int b = fi % B_DIM, s = fi / B_DIM;
    const float* x = inp + ((size_t)b * S_DIM + s) * D_DIM;

    for (int k = lane; k < 324; k += 64) {
        float ang = (k < 54)  ? x[k]
                  : (k < 144) ? wq[k - 54]
                  : (k < 234) ? wk[k - 144]
                              : wv[k - 234];
        float sn, cn; sincosf(0.5f * ang, &sn, &cn);
        _Float16 hc = (_Float16)cn, hs = (_Float16)sn;
        h2 c2 = {hc, hc}, s2 = {hs, hs};
        csc[k] = h2i(c2);
        css[k] = h2i(s2);
    }
    // single wave: LDS write->read ordering handled by lgkmcnt, no barrier needed

    h2 st[3][8];
#pragma unroll
    for (int r = 0; r < 8; ++r) st[0][r] = i2h(0);
    if (lane == 0) { h2 one = {(_Float16)1.f, (_Float16)0.f}; st[0][0] = one; }

    // ---- Encoding circuit on st[0] (NP=1) ----
#define EINIT(j) { int c1[1] = {csc[2*(j)]},     s1[1] = {css[2*(j)]};      \
                   rot_rxN<1, 8-(j)>(st, c1, s1, lane);                     \
                   int c1b[1] = {csc[2*(j)+1]},  s1b[1] = {css[2*(j)+1]};   \
                   rot_ryN<1, 8-(j)>(st, c1b, s1b, lane); }
    EINIT(0) EINIT(1) EINIT(2) EINIT(3) EINIT(4)
    EINIT(5) EINIT(6) EINIT(7) EINIT(8)
#undef EINIT
    {
        const int* pc = csc + 18;
        const int* ps = css + 18;
#pragma unroll 1
        for (int L = 0; L < DENC; ++L) {
            ringN<1>(st, lane);
#define ERY(i, BJ) { int c1[1] = {pc[i]}, s1[1] = {ps[i]}; rot_ryN<1, BJ>(st, c1, s1, lane); }
            ERY(0, 8) ERY(1, 7) ERY(2, 6) ERY(3, 5) ERY(4, 4)
            ERY(5, 3) ERY(6, 2) ERY(7, 1) ERY(8, 0)
#undef ERY
            pc += 9; ps += 9;
        }
    }

    // Fork: st[1] = st[2] = st[0]
#pragma unroll
    for (int r = 0; r < 8; ++r) { st[1][r] = st[0][r]; st[2][r] = st[0][r]; }

    // ---- Three variational circuits interleaved (st[0]=Q, st[1]=K, st[2]=V) ----
    {
        const int* cq = csc + 54;  const int* sq_ = css + 54;
        const int* ck_ = csc + 144; const int* sk_ = css + 144;
        const int* cv = csc + 234; const int* sv_ = css + 234;
#define VINIT(j) { int c3[3] = {cq[2*(j)],   ck_[2*(j)],   cv[2*(j)]};      \
                   int s3[3] = {sq_[2*(j)],  sk_[2*(j)],   sv_[2*(j)]};     \
                   rot_rxN<3, 8-(j)>(st, c3, s3, lane);                     \
                   int c3b[3] = {cq[2*(j)+1], ck_[2*(j)+1], cv[2*(j)+1]};   \
                   int s3b[3] = {sq_[2*(j)+1], sk_[2*(j)+1], sv_[2*(j)+1]}; \
                   rot_ryN<3, 8-(j)>(st, c3b, s3b, lane); }
        VINIT(0) VINIT(1) VINIT(2) VINIT(3) VINIT(4)
        VINIT(5) VINIT(6) VINIT(7) VINIT(8)
#undef VINIT
        const int* pcq = cq + 18;  const int* psq = sq_ + 18;
        const int* pck = ck_ + 18; const int* psk = sk_ + 18;
        const int* pcv = cv + 18;  const int* psv = sv_ + 18;
#pragma unroll 1
        for (int L = 0; L < DVAR; ++L) {
            ringN<3>(st, lane);
#define VRY(i, BJ) { int c3[3] = {pcq[i], pck[i], pcv[i]};                  \
                     int s3[3] = {psq[i], psk[i], psv[i]};                  \
                     rot_ryN<3, BJ>(st, c3, s3, lane); }
            VRY(0, 8) VRY(1, 7) VRY(2, 6) VRY(3, 5) VRY(4, 4)
            VRY(5, 3) VRY(6, 2) VRY(7, 1) VRY(8, 0)
#undef VRY
            pcq += 9; psq += 9; pck += 9; psk += 9; pcv += 9; psv += 9;
        }
    }

    // ---- Q: <Z_0> (qubit 0 = state bit 8 = lane bit 5) ----
    {
        float p = 0.f;
#pragma unroll
        for (int r = 0; r < 8; ++r) {
            float xx = (float)st[0][r].x, yy = (float)st[0][r].y;
            p += xx * xx + yy * yy;
        }
        p = (lane & 32) ? -p : p;
        p = wave_sum(p, lane);
        if (lane == 0) outQ[fi] = p;
    }
    // ---- K ----
    {
        float p = 0.f;
#pragma unroll
        for (int r = 0; r < 8; ++r) {
            float xx = (float)st[1][r].x, yy = (float)st[1][r].y;
            p += xx * xx + yy * yy;
        }
        p = (lane & 32) ? -p : p;
        p = wave_sum(p, lane);
        if (lane == 0) outK[fi] = p;
    }
    // ---- V ----
    {
        float* vrow = outV + (size_t)fi * D_DIM;
#define EXPQ(q) { float ez, ex, ey; expv<8 - (q)>(st[2], lane, ez, ex, ey);         \
                  if (lane == 0) { vrow[(q)] = ez; vrow[9 + (q)] = ex;              \
                                   vrow[18 + (q)] = ey; vrow[27 + (q)] = ez;        \
                                   vrow[36 + (q)] = ex; vrow[45 + (q)] = ey; } }
        EXPQ(0) EXPQ(1) EXPQ(2) EXPQ(3) EXPQ(4)
        EXPQ(5) EXPQ(6) EXPQ(7) EXPQ(8)
#undef EXPQ
    }
}

__global__ __launch_bounds__(256) void attn_kernel(
    const float* __restrict__ inp, const float* __restrict__ Q,
    const float* __restrict__ K,   const float* __restrict__ V,
    float* __restrict__ out)
{
    __shared__ float w4[4][S_DIM];
    const int warp = threadIdx.x >> 6;
    const int t    = threadIdx.x & 63;
    const int bi   = blockIdx.x * 4 + warp;   // b*S + i
    const int b    = bi / S_DIM;
    const int i    = bi % S_DIM;
    float* w = w4[warp];

    const float q = Q[i * B_DIM + b];
    float e0, e1 = 0.f;
    {
        float d0 = q - K[t * B_DIM + b];
        e0 = expf(-d0 * d0);
        w[t] = e0;
        if (t < S_DIM - 64) {
            float d1 = q - K[(t + 64) * B_DIM + b];
            e1 = expf(-d1 * d1);
            w[t + 64] = e1;
        }
    }
    float ps = wave_sum(e0 + e1, t);
    const float inv = 1.f / ps;

    if (t < D_DIM) {
        float acc = 0.f;
        for (int j = 0; j < S_DIM; ++j)
            acc += w[j] * V[(size_t)(j * B_DIM + b) * D_DIM + t];
        size_t o = (size_t)bi * D_DIM + t;
        out[o] = inp[o] + acc * inv;
    }
}

extern "C" void kernel_launch(void* const* d_in, const int* in_sizes, int n_in,
                              void* d_out, int out_size, void* d_ws, size_t ws_size,
                              hipStream_t stream)
{
    (void)in_sizes; (void)n_in; (void)out_size; (void)ws_size;
    const float* inp = (const float*)d_in[0];
    const float* wq  = (const float*)d_in[1];
    const float* wk  = (const float*)d_in[2];
    const float* wv  = (const float*)d_in[3];
    float* outp = (float*)d_out;

    float* Qw = (float*)d_ws;
    float* Kw = Qw + NFLAT;
    float* Vw = Kw + NFLAT;

    sim_kernel<<<NFLAT, 64, 0, stream>>>(inp, wq, wk, wv, Qw, Kw, Vw);
    attn_kernel<<<NFLAT / 4, 256, 0, stream>>>(inp, Qw, Kw, Vw, outp);
}